// Round 17
// baseline (53.718 us; speedup 1.0000x reference)
//
#include <hip/hip_runtime.h>
#include <hip/hip_bf16.h>

typedef unsigned short u16;
typedef unsigned int u32;
typedef __attribute__((ext_vector_type(8))) short bf16x8;
typedef __attribute__((ext_vector_type(4))) float f32x4;

#define NTOK 4096
// 0.125 (1/sqrt(64)) * log2(e): folded into Qt so QK^T lands in exp2 domain
#define QSCALE2 0.18033688f

__device__ __forceinline__ float b2f(u16 u) {
    u32 v = ((u32)u) << 16;
    return __builtin_bit_cast(float, v);
}
__device__ __forceinline__ u16 f2b(float f) {
    u32 u = __builtin_bit_cast(u32, f);
    u32 r = (u + 0x7fffu + ((u >> 16) & 1u)) >> 16;  // RNE
    return (u16)r;
}
__device__ __forceinline__ u32 pack2(float lo, float hi) {
    return (u32)f2b(lo) | ((u32)f2b(hi) << 16);
}
// compiler-visible pair conversion -> v_cvt_pk_bf16_f32
__device__ __forceinline__ u32 pk2(float lo, float hi) {
    float2 t; t.x = lo; t.y = hi;
    __hip_bfloat162 b = __float22bfloat162_rn(t);
    u32 r;
    __builtin_memcpy(&r, &b, 4);
    return r;
}
__device__ __forceinline__ bf16x8 cvt8(const float* __restrict__ p) {
    float4 a = *(const float4*)p;
    float4 b = *(const float4*)(p + 4);
    bf16x8 r;
    r[0] = (short)f2b(a.x); r[1] = (short)f2b(a.y);
    r[2] = (short)f2b(a.z); r[3] = (short)f2b(a.w);
    r[4] = (short)f2b(b.x); r[5] = (short)f2b(b.y);
    r[6] = (short)f2b(b.z); r[7] = (short)f2b(b.w);
    return r;
}

// ---------------------------------------------------------------------------
// Kernel 1: QKV projection (identical to verified r13/r14).
// Kfrag in QK-fragment order [b][kb(128)][f(4)][lane(64)][8];
// Vswz in PV-fragment order [b][kb(128)][cb(4)][lane(64)][8].
// ---------------------------------------------------------------------------
__global__ __launch_bounds__(512) void qkv_kernel(
    const float* __restrict__ seg, const float* __restrict__ gau,
    const float* __restrict__ Wq, const float* __restrict__ bq,
    const float* __restrict__ Wk, const float* __restrict__ bk,
    const float* __restrict__ Wv, const float* __restrict__ bv,
    u16* __restrict__ Qt, u16* __restrict__ Kfrag,
    u16* __restrict__ Vtok, u16* __restrict__ Vswz)
{
    __shared__ __align__(16) u16 sSegT[64 * 64];
    __shared__ __align__(16) u16 sGauT[64 * 64];
    __shared__ __align__(16) u16 kBuf[64 * 64];
    const int tid = threadIdx.x;
    const int bid = blockIdx.x;            // 0..255
    const int xcd = bid & 7;
    const int b = xcd >> 1;
    const int nb = ((bid >> 3) << 1) | (xcd & 1);   // 0..63
    const int n0 = nb * 64;

    for (int idx = tid; idx < 4096; idx += 512) {
        int c = idx >> 6, t = idx & 63;
        int sw = t * 64 + ((((c >> 3) ^ (t & 7)) << 3) | (c & 7));
        sSegT[sw] = f2b(seg[(size_t)(b * 64 + c) * NTOK + n0 + t]);
        sGauT[sw] = f2b(gau[(size_t)(b * 64 + c) * NTOK + n0 + t]);
    }
    __syncthreads();

    const int lane = tid & 63;
    const int wv = tid >> 6;
    const int tb = wv & 3;
    const int task = wv >> 2;
    const int q = lane & 15, g = lane >> 4;
    const int tok = tb * 16 + q;

    const size_t obase = (size_t)b * NTOK * 64;
    const size_t rowb = (size_t)(n0 + tb * 16 + g * 4);

    if (task == 0) {
        bf16x8 as[2];
#pragma unroll
        for (int ks = 0; ks < 2; ++ks) {
            int c0 = ks * 32 + g * 8;
            int sw = tok * 64 + (((c0 >> 3) ^ (tok & 7)) << 3);
            as[ks] = *(const bf16x8*)&sSegT[sw];
        }
#pragma unroll
        for (int ob = 0; ob < 4; ++ob) {
            int o = ob * 16 + q;
            {
                float bias = bq[o];
                f32x4 acc = {bias, bias, bias, bias};
                bf16x8 w0 = cvt8(&Wq[o * 64 + g * 8]);
                bf16x8 w1 = cvt8(&Wq[o * 64 + 32 + g * 8]);
                acc = __builtin_amdgcn_mfma_f32_16x16x32_bf16(as[0], w0, acc, 0, 0, 0);
                acc = __builtin_amdgcn_mfma_f32_16x16x32_bf16(as[1], w1, acc, 0, 0, 0);
#pragma unroll
                for (int j = 0; j < 4; ++j)
                    Qt[obase + (rowb + j) * 64 + o] = f2b(acc[j] * QSCALE2);
            }
            {
                float bias = bk[o];
                f32x4 acc = {bias, bias, bias, bias};
                bf16x8 w0 = cvt8(&Wk[o * 64 + g * 8]);
                bf16x8 w1 = cvt8(&Wk[o * 64 + 32 + g * 8]);
                acc = __builtin_amdgcn_mfma_f32_16x16x32_bf16(as[0], w0, acc, 0, 0, 0);
                acc = __builtin_amdgcn_mfma_f32_16x16x32_bf16(as[1], w1, acc, 0, 0, 0);
#pragma unroll
                for (int j = 0; j < 4; ++j)
                    kBuf[(tb * 16 + g * 4 + j) * 64 + o] = f2b(acc[j]);
            }
        }
    } else {
        bf16x8 ag[2];
#pragma unroll
        for (int ks = 0; ks < 2; ++ks) {
            int c0 = ks * 32 + g * 8;
            int sw = tok * 64 + (((c0 >> 3) ^ (tok & 7)) << 3);
            ag[ks] = *(const bf16x8*)&sGauT[sw];
        }
        const int kbg = (n0 >> 5) + (tb >> 1);
        const int half = tb & 1;
#pragma unroll
        for (int ob = 0; ob < 4; ++ob) {
            int o = ob * 16 + q;
            float bias = bv[o];
            f32x4 acc = {bias, bias, bias, bias};
            bf16x8 w0 = cvt8(&Wv[o * 64 + g * 8]);
            bf16x8 w1 = cvt8(&Wv[o * 64 + 32 + g * 8]);
            acc = __builtin_amdgcn_mfma_f32_16x16x32_bf16(ag[0], w0, acc, 0, 0, 0);
            acc = __builtin_amdgcn_mfma_f32_16x16x32_bf16(ag[1], w1, acc, 0, 0, 0);
            ushort4 v4;
            v4.x = f2b(acc[0]); v4.y = f2b(acc[1]);
            v4.z = f2b(acc[2]); v4.w = f2b(acc[3]);
#pragma unroll
            for (int j = 0; j < 4; ++j)
                Vtok[obase + (rowb + j) * 64 + o] = f2b(acc[j]);
            *(ushort4*)&Vswz[(((size_t)(b * 128 + kbg)) * 4 + ob) * 512 + lane * 8 + half * 4] = v4;
        }
    }
    __syncthreads();

    // Kfrag scatter: one ushort8 per thread
    {
        const int F = (wv * 64 + lane) * 8;
        const int kb2 = F >> 11;
        const int f = (F >> 9) & 3;
        const int l2 = (F >> 3) & 63;
        const int R = kb2 * 32 + ((f >> 1) << 4) + (l2 & 15);
        const int c0 = ((f & 1) << 5) + ((l2 >> 4) << 3);
        bf16x8 v = *(const bf16x8*)&kBuf[R * 64 + c0];
        *(bf16x8*)&Kfrag[(((size_t)(b * 128 + nb * 2 + kb2)) * 4 + f) * 512 + l2 * 8] = v;
    }
}

// ---------------------------------------------------------------------------
// Kernel 2: flash attention + LN1 + FFN + LN2.
// 256 blocks x 512 threads (8 waves) = 1 block/CU, one round.
// Block = 64 queries (4 groups of 16 per wave), 8-way K-split.
// A/B vs r14: NO LDS staging — K/V fragments loaded DIRECTLY from the
// fragment-ordered global layouts (1KB coalesced loads). Removes 128KB/iter
// LDS roundtrip traffic + vmcnt ordering; 4-group compute (~1600cyc/tile)
// amortizes the exposed L2 latency that killed this pattern pre-r14.
// ---------------------------------------------------------------------------
__global__ __launch_bounds__(512, 2) void attn_kernel(
    const u16* __restrict__ Qt, const u16* __restrict__ Kfrag,
    const u16* __restrict__ Vtok, const u16* __restrict__ Vswz,
    const float* __restrict__ ln1w, const float* __restrict__ ln1b,
    const float* __restrict__ ln2w, const float* __restrict__ ln2b,
    const float* __restrict__ W1, const float* __restrict__ b1,
    const float* __restrict__ W2, const float* __restrict__ b2,
    float* __restrict__ out)
{
    __shared__ __align__(16) float sAccS[4][64][68];  // 69632 B
    __shared__ __align__(16) u16 sX[4 * 16 * 64];     // 8KB
    __shared__ float sL[8][64];                       // 2KB

    const int tid = threadIdx.x;
    const int wv = tid >> 6;          // 0..7 (K-split)
    const int lane = tid & 63;
    const int q = lane & 15, g = lane >> 4;
    const int bid = blockIdx.x;       // 0..255
    const int xcd = bid & 7;
    const int b = xcd >> 1;
    const int qb = ((bid >> 3) << 1) | (xcd & 1);   // 0..63
    const int q0 = qb * 64;
    const size_t tb_ = (size_t)b * NTOK * 64;

    // Q fragments for 4 query groups (Qt pre-scaled to exp2 domain)
    bf16x8 qf[4][2];
#pragma unroll
    for (int gi = 0; gi < 4; ++gi) {
        const size_t r = tb_ + (size_t)(q0 + gi * 16 + q) * 64;
        qf[gi][0] = *(const bf16x8*)&Qt[r + g * 8];
        qf[gi][1] = *(const bf16x8*)&Qt[r + 32 + g * 8];
    }

    f32x4 zero4 = {0.f, 0.f, 0.f, 0.f};
    f32x4 acc[4][4];
#pragma unroll
    for (int gi = 0; gi < 4; ++gi)
#pragma unroll
        for (int cb = 0; cb < 4; ++cb) acc[gi][cb] = zero4;
    float l[4] = {0.f, 0.f, 0.f, 0.f};

    const int kbeg = wv * 512;
    const size_t kvb = ((size_t)(b * 128 + (kbeg >> 5))) * 2048;
    const u16* gK = Kfrag + kvb + lane * 8;
    const u16* gV = Vswz + kvb + lane * 8;

    for (int it = 0; it < 16; ++it) {
        const u16* kt = gK + (size_t)it * 2048;
        const u16* vt = gV + (size_t)it * 2048;
        // direct fragment loads: 8 x coalesced 1KB global_load_dwordx4
        bf16x8 kf00 = *(const bf16x8*)&kt[0 * 512];
        bf16x8 kf01 = *(const bf16x8*)&kt[1 * 512];
        bf16x8 kf10 = *(const bf16x8*)&kt[2 * 512];
        bf16x8 kf11 = *(const bf16x8*)&kt[3 * 512];
        bf16x8 vf0 = *(const bf16x8*)&vt[0 * 512];
        bf16x8 vf1 = *(const bf16x8*)&vt[1 * 512];
        bf16x8 vf2 = *(const bf16x8*)&vt[2 * 512];
        bf16x8 vf3 = *(const bf16x8*)&vt[3 * 512];

        // ---- 4 independent query groups over this 32-key tile ----
#pragma unroll
        for (int gi = 0; gi < 4; ++gi) {
            f32x4 s0 = __builtin_amdgcn_mfma_f32_16x16x32_bf16(kf00, qf[gi][0], zero4, 0, 0, 0);
            s0 = __builtin_amdgcn_mfma_f32_16x16x32_bf16(kf01, qf[gi][1], s0, 0, 0, 0);
            f32x4 s1 = __builtin_amdgcn_mfma_f32_16x16x32_bf16(kf10, qf[gi][0], zero4, 0, 0, 0);
            s1 = __builtin_amdgcn_mfma_f32_16x16x32_bf16(kf11, qf[gi][1], s1, 0, 0, 0);

            float p0 = __builtin_exp2f(s0[0]);
            float p1 = __builtin_exp2f(s0[1]);
            float p2 = __builtin_exp2f(s0[2]);
            float p3 = __builtin_exp2f(s0[3]);
            float p4 = __builtin_exp2f(s1[0]);
            float p5 = __builtin_exp2f(s1[1]);
            float p6 = __builtin_exp2f(s1[2]);
            float p7 = __builtin_exp2f(s1[3]);
            l[gi] += ((p0 + p1) + (p2 + p3)) + ((p4 + p5) + (p6 + p7));
            u32 pwv[4] = {pk2(p0, p1), pk2(p2, p3), pk2(p4, p5), pk2(p6, p7)};
            bf16x8 pf = __builtin_bit_cast(bf16x8, *(const bf16x8*)pwv);
            acc[gi][0] = __builtin_amdgcn_mfma_f32_16x16x32_bf16(vf0, pf, acc[gi][0], 0, 0, 0);
            acc[gi][1] = __builtin_amdgcn_mfma_f32_16x16x32_bf16(vf1, pf, acc[gi][1], 0, 0, 0);
            acc[gi][2] = __builtin_amdgcn_mfma_f32_16x16x32_bf16(vf2, pf, acc[gi][2], 0, 0, 0);
            acc[gi][3] = __builtin_amdgcn_mfma_f32_16x16x32_bf16(vf3, pf, acc[gi][3], 0, 0, 0);
        }
    }

    // cross-lane l reduction (g-lanes of each query), once
#pragma unroll
    for (int gi = 0; gi < 4; ++gi) {
        l[gi] += __shfl_xor(l[gi], 16);
        l[gi] += __shfl_xor(l[gi], 32);
    }

    float* sAcc = (float*)sAccS;
#define SACC(w_, r_) (&sAcc[(((w_) * 64) + (r_)) * 68])

    // ---- stage 1: waves 4-7 publish partials ----
    if (wv >= 4) {
        const int s = wv - 4;
#pragma unroll
        for (int gi = 0; gi < 4; ++gi) {
            sL[wv][gi * 16 + q] = l[gi];
#pragma unroll
            for (int cb = 0; cb < 4; ++cb)
                *(f32x4*)&SACC(s, gi * 16 + q)[cb * 16 + g * 4] = acc[gi][cb];
        }
    }
    __syncthreads();

    // ---- stage 2: waves 0-3 add partner (wv+4), publish ----
    if (wv < 4) {
#pragma unroll
        for (int gi = 0; gi < 4; ++gi) {
            l[gi] += sL[wv + 4][gi * 16 + q];
            sL[wv][gi * 16 + q] = l[gi];
#pragma unroll
            for (int cb = 0; cb < 4; ++cb) {
                f32x4 pa = *(const f32x4*)&SACC(wv, gi * 16 + q)[cb * 16 + g * 4];
#pragma unroll
                for (int j = 0; j < 4; ++j) acc[gi][cb][j] += pa[j];
                *(f32x4*)&SACC(wv, gi * 16 + q)[cb * 16 + g * 4] = acc[gi][cb];
            }
        }
    }
    __syncthreads();
    if (wv >= 4) return;

    // ---- stage 3: waves 0-3, each finishes 16 queries qe = wv*16+q ----
    const int qe = wv * 16 + q;
    const int n_q = q0 + qe;

    float L = sL[0][qe] + sL[1][qe] + sL[2][qe] + sL[3][qe];
    f32x4 o[4];
#pragma unroll
    for (int cb = 0; cb < 4; ++cb) o[cb] = zero4;
#pragma unroll
    for (int w = 0; w < 4; ++w) {
#pragma unroll
        for (int cb = 0; cb < 4; ++cb) {
            f32x4 aw = *(const f32x4*)&SACC(w, qe)[cb * 16 + g * 4];
#pragma unroll
            for (int j = 0; j < 4; ++j) o[cb][j] += aw[j];
        }
    }

    float inv_l = 1.0f / L;
    float x1[4][4];
#pragma unroll
    for (int cb = 0; cb < 4; ++cb) {
        ushort4 vv = *(const ushort4*)&Vtok[tb_ + (size_t)n_q * 64 + cb * 16 + g * 4];
        x1[cb][0] = o[cb][0] * inv_l + b2f(vv.x);
        x1[cb][1] = o[cb][1] * inv_l + b2f(vv.y);
        x1[cb][2] = o[cb][2] * inv_l + b2f(vv.z);
        x1[cb][3] = o[cb][3] * inv_l + b2f(vv.w);
    }

    // LN1
    float s_ = 0.f;
#pragma unroll
    for (int cb = 0; cb < 4; ++cb)
        for (int j = 0; j < 4; ++j) s_ += x1[cb][j];
    s_ += __shfl_xor(s_, 16); s_ += __shfl_xor(s_, 32);
    float mean = s_ * (1.f / 64.f);
    float v_ = 0.f;
#pragma unroll
    for (int cb = 0; cb < 4; ++cb)
        for (int j = 0; j < 4; ++j) { float d = x1[cb][j] - mean; v_ += d * d; }
    v_ += __shfl_xor(v_, 16); v_ += __shfl_xor(v_, 32);
    float rstd = rsqrtf(v_ * (1.f / 64.f) + 1e-5f);

    float xh[4][4];
#pragma unroll
    for (int cb = 0; cb < 4; ++cb) {
        float4 lw = *(const float4*)&ln1w[cb * 16 + g * 4];
        float4 lb = *(const float4*)&ln1b[cb * 16 + g * 4];
        xh[cb][0] = (x1[cb][0] - mean) * rstd * lw.x + lb.x;
        xh[cb][1] = (x1[cb][1] - mean) * rstd * lw.y + lb.y;
        xh[cb][2] = (x1[cb][2] - mean) * rstd * lw.z + lb.z;
        xh[cb][3] = (x1[cb][3] - mean) * rstd * lw.w + lb.w;
    }

    // FFN layer 1 via per-wave LDS roundtrip
    u32* sXu = (u32*)sX;
    const int xwr = wv * 512 + q * 32;
#pragma unroll
    for (int cb = 0; cb < 4; ++cb) {
        sXu[xwr + cb * 8 + g * 2 + 0] = pack2(xh[cb][0], xh[cb][1]);
        sXu[xwr + cb * 8 + g * 2 + 1] = pack2(xh[cb][2], xh[cb][3]);
    }
    asm volatile("s_waitcnt lgkmcnt(0)" ::: "memory");
    __builtin_amdgcn_sched_barrier(0);
    const u16* xrp = &sX[wv * 1024 + q * 64 + g * 8];
    bf16x8 xb0 = *(const bf16x8*)&xrp[0];
    bf16x8 xb1 = *(const bf16x8*)&xrp[32];

    float h[4][4];
#pragma unroll
    for (int ob = 0; ob < 4; ++ob) {
        float4 bb = *(const float4*)&b1[ob * 16 + g * 4];
        f32x4 hacc = {bb.x, bb.y, bb.z, bb.w};
        bf16x8 w0 = cvt8(&W1[(size_t)(ob * 16 + q) * 64 + g * 8]);
        bf16x8 w1 = cvt8(&W1[(size_t)(ob * 16 + q) * 64 + 32 + g * 8]);
        hacc = __builtin_amdgcn_mfma_f32_16x16x32_bf16(w0, xb0, hacc, 0, 0, 0);
        hacc = __builtin_amdgcn_mfma_f32_16x16x32_bf16(w1, xb1, hacc, 0, 0, 0);
#pragma unroll
        for (int j = 0; j < 4; ++j) h[ob][j] = fmaxf(hacc[j], 0.f);
    }

#pragma unroll
    for (int ob = 0; ob < 4; ++ob) {
        sXu[xwr + ob * 8 + g * 2 + 0] = pack2(h[ob][0], h[ob][1]);
        sXu[xwr + ob * 8 + g * 2 + 1] = pack2(h[ob][2], h[ob][3]);
    }
    asm volatile("s_waitcnt lgkmcnt(0)" ::: "memory");
    __builtin_amdgcn_sched_barrier(0);
    bf16x8 hb0 = *(const bf16x8*)&xrp[0];
    bf16x8 hb1 = *(const bf16x8*)&xrp[32];

    float f_[4][4];
#pragma unroll
    for (int cb = 0; cb < 4; ++cb) {
        float4 bb = *(const float4*)&b2[cb * 16 + g * 4];
        f32x4 yacc = {bb.x, bb.y, bb.z, bb.w};
        bf16x8 w0 = cvt8(&W2[(size_t)(cb * 16 + q) * 64 + g * 8]);
        bf16x8 w1 = cvt8(&W2[(size_t)(cb * 16 + q) * 64 + 32 + g * 8]);
        yacc = __builtin_amdgcn_mfma_f32_16x16x32_bf16(w0, hb0, yacc, 0, 0, 0);
        yacc = __builtin_amdgcn_mfma_f32_16x16x32_bf16(w1, hb1, yacc, 0, 0, 0);
#pragma unroll
        for (int j = 0; j < 4; ++j) f_[cb][j] = xh[cb][j] + yacc[j];
    }

    // LN2
    float s2 = 0.f;
#pragma unroll
    for (int cb = 0; cb < 4; ++cb)
        for (int j = 0; j < 4; ++j) s2 += f_[cb][j];
    s2 += __shfl_xor(s2, 16); s2 += __shfl_xor(s2, 32);
    float mean2 = s2 * (1.f / 64.f);
    float v2 = 0.f;
#pragma unroll
    for (int cb = 0; cb < 4; ++cb)
        for (int j = 0; j < 4; ++j) { float d = f_[cb][j] - mean2; v2 += d * d; }
    v2 += __shfl_xor(v2, 16); v2 += __shfl_xor(v2, 32);
    float rstd2 = rsqrtf(v2 * (1.f / 64.f) + 1e-5f);

#pragma unroll
    for (int cb = 0; cb < 4; ++cb) {
        float4 lw = *(const float4*)&ln2w[cb * 16 + g * 4];
        float4 lb = *(const float4*)&ln2b[cb * 16 + g * 4];
        float o0 = (f_[cb][0] - mean2) * rstd2 * lw.x + lb.x;
        float o1 = (f_[cb][1] - mean2) * rstd2 * lw.y + lb.y;
        float o2 = (f_[cb][2] - mean2) * rstd2 * lw.z + lb.z;
        float o3 = (f_[cb][3] - mean2) * rstd2 * lw.w + lb.w;
        out[(size_t)(b * 64 + cb * 16 + g * 4 + 0) * NTOK + n_q] = o0;
        out[(size_t)(b * 64 + cb * 16 + g * 4 + 1) * NTOK + n_q] = o1;
        out[(size_t)(b * 64 + cb * 16 + g * 4 + 2) * NTOK + n_q] = o2;
        out[(size_t)(b * 64 + cb * 16 + g * 4 + 3) * NTOK + n_q] = o3;
    }
}

extern "C" void kernel_launch(void* const* d_in, const int* in_sizes, int n_in,
                              void* d_out, int out_size, void* d_ws, size_t ws_size,
                              hipStream_t stream) {
    const float* seg = (const float*)d_in[0];
    const float* gau = (const float*)d_in[1];
    const float* Wq = (const float*)d_in[2];
    const float* bq = (const float*)d_in[3];
    const float* Wk = (const float*)d_in[4];
    const float* bk = (const float*)d_in[5];
    const float* Wv = (const float*)d_in[6];
    const float* bv = (const float*)d_in[7];
    const float* ln1w = (const float*)d_in[8];
    const float* ln1b = (const float*)d_in[9];
    const float* ln2w = (const float*)d_in[10];
    const float* ln2b = (const float*)d_in[11];
    const float* W1 = (const float*)d_in[12];
    const float* b1 = (const float*)d_in[13];
    const float* W2 = (const float*)d_in[14];
    const float* b2 = (const float*)d_in[15];

    u16* Qt = (u16*)d_ws;
    u16* Kfrag = Qt + (size_t)4 * NTOK * 64;    // [b][kb(128)][f(4)][lane(64)][8]
    u16* Vtok = Kfrag + (size_t)4 * NTOK * 64;
    u16* Vswz = Vtok + (size_t)4 * NTOK * 64;   // [b][kb(128)][cb(4)][lane(64)][8]
    float* outp = (float*)d_out;

    hipLaunchKernelGGL(qkv_kernel, dim3(256), dim3(512), 0, stream,
                       seg, gau, Wq, bq, Wk, bk, Wv, bv, Qt, Kfrag, Vtok, Vswz);
    hipLaunchKernelGGL(attn_kernel, dim3(256), dim3(512), 0, stream,
                       Qt, Kfrag, Vtok, Vswz, ln1w, ln1b, ln2w, ln2b,
                       W1, b1, W2, b2, outp);
}

// Round 18
// 52.260 us; speedup vs baseline: 1.0279x; 1.0279x over previous
//
#include <hip/hip_runtime.h>
#include <hip/hip_bf16.h>

typedef unsigned short u16;
typedef unsigned int u32;
typedef __attribute__((ext_vector_type(8))) short bf16x8;
typedef __attribute__((ext_vector_type(4))) float f32x4;

#define NTOK 4096
// 0.125 (1/sqrt(64)) * log2(e): folded into Qt so QK^T lands in exp2 domain
#define QSCALE2 0.18033688f

// async global->LDS, 16B per lane (dest = wave-uniform base + lane*16)
#define GLD_LDS(g, l) __builtin_amdgcn_global_load_lds( \
    (const __attribute__((address_space(1))) void*)(g), \
    (__attribute__((address_space(3))) void*)(l), 16, 0, 0)

typedef __attribute__((address_space(3))) const u16 lds_cu16;

__device__ __forceinline__ float b2f(u16 u) {
    u32 v = ((u32)u) << 16;
    return __builtin_bit_cast(float, v);
}
__device__ __forceinline__ u16 f2b(float f) {
    u32 u = __builtin_bit_cast(u32, f);
    u32 r = (u + 0x7fffu + ((u >> 16) & 1u)) >> 16;  // RNE
    return (u16)r;
}
__device__ __forceinline__ u32 pack2(float lo, float hi) {
    return (u32)f2b(lo) | ((u32)f2b(hi) << 16);
}
// compiler-visible pair conversion -> v_cvt_pk_bf16_f32
__device__ __forceinline__ u32 pk2(float lo, float hi) {
    float2 t; t.x = lo; t.y = hi;
    __hip_bfloat162 b = __float22bfloat162_rn(t);
    u32 r;
    __builtin_memcpy(&r, &b, 4);
    return r;
}
__device__ __forceinline__ bf16x8 cvt8(const float* __restrict__ p) {
    float4 a = *(const float4*)p;
    float4 b = *(const float4*)(p + 4);
    bf16x8 r;
    r[0] = (short)f2b(a.x); r[1] = (short)f2b(a.y);
    r[2] = (short)f2b(a.z); r[3] = (short)f2b(a.w);
    r[4] = (short)f2b(b.x); r[5] = (short)f2b(b.y);
    r[6] = (short)f2b(b.z); r[7] = (short)f2b(b.w);
    return r;
}

// ---------------------------------------------------------------------------
// Kernel 1: QKV projection (identical to verified r13/r14).
// Kfrag in QK-fragment order [b][kb(128)][f(4)][lane(64)][8];
// Vswz in PV-fragment order [b][kb(128)][cb(4)][lane(64)][8].
// ---------------------------------------------------------------------------
__global__ __launch_bounds__(512) void qkv_kernel(
    const float* __restrict__ seg, const float* __restrict__ gau,
    const float* __restrict__ Wq, const float* __restrict__ bq,
    const float* __restrict__ Wk, const float* __restrict__ bk,
    const float* __restrict__ Wv, const float* __restrict__ bv,
    u16* __restrict__ Qt, u16* __restrict__ Kfrag,
    u16* __restrict__ Vtok, u16* __restrict__ Vswz)
{
    __shared__ __align__(16) u16 sSegT[64 * 64];
    __shared__ __align__(16) u16 sGauT[64 * 64];
    __shared__ __align__(16) u16 kBuf[64 * 64];
    const int tid = threadIdx.x;
    const int bid = blockIdx.x;            // 0..255
    const int xcd = bid & 7;
    const int b = xcd >> 1;
    const int nb = ((bid >> 3) << 1) | (xcd & 1);   // 0..63
    const int n0 = nb * 64;

    for (int idx = tid; idx < 4096; idx += 512) {
        int c = idx >> 6, t = idx & 63;
        int sw = t * 64 + ((((c >> 3) ^ (t & 7)) << 3) | (c & 7));
        sSegT[sw] = f2b(seg[(size_t)(b * 64 + c) * NTOK + n0 + t]);
        sGauT[sw] = f2b(gau[(size_t)(b * 64 + c) * NTOK + n0 + t]);
    }
    __syncthreads();

    const int lane = tid & 63;
    const int wv = tid >> 6;
    const int tb = wv & 3;
    const int task = wv >> 2;
    const int q = lane & 15, g = lane >> 4;
    const int tok = tb * 16 + q;

    const size_t obase = (size_t)b * NTOK * 64;
    const size_t rowb = (size_t)(n0 + tb * 16 + g * 4);

    if (task == 0) {
        bf16x8 as[2];
#pragma unroll
        for (int ks = 0; ks < 2; ++ks) {
            int c0 = ks * 32 + g * 8;
            int sw = tok * 64 + (((c0 >> 3) ^ (tok & 7)) << 3);
            as[ks] = *(const bf16x8*)&sSegT[sw];
        }
#pragma unroll
        for (int ob = 0; ob < 4; ++ob) {
            int o = ob * 16 + q;
            {
                float bias = bq[o];
                f32x4 acc = {bias, bias, bias, bias};
                bf16x8 w0 = cvt8(&Wq[o * 64 + g * 8]);
                bf16x8 w1 = cvt8(&Wq[o * 64 + 32 + g * 8]);
                acc = __builtin_amdgcn_mfma_f32_16x16x32_bf16(as[0], w0, acc, 0, 0, 0);
                acc = __builtin_amdgcn_mfma_f32_16x16x32_bf16(as[1], w1, acc, 0, 0, 0);
#pragma unroll
                for (int j = 0; j < 4; ++j)
                    Qt[obase + (rowb + j) * 64 + o] = f2b(acc[j] * QSCALE2);
            }
            {
                float bias = bk[o];
                f32x4 acc = {bias, bias, bias, bias};
                bf16x8 w0 = cvt8(&Wk[o * 64 + g * 8]);
                bf16x8 w1 = cvt8(&Wk[o * 64 + 32 + g * 8]);
                acc = __builtin_amdgcn_mfma_f32_16x16x32_bf16(as[0], w0, acc, 0, 0, 0);
                acc = __builtin_amdgcn_mfma_f32_16x16x32_bf16(as[1], w1, acc, 0, 0, 0);
#pragma unroll
                for (int j = 0; j < 4; ++j)
                    kBuf[(tb * 16 + g * 4 + j) * 64 + o] = f2b(acc[j]);
            }
        }
    } else {
        bf16x8 ag[2];
#pragma unroll
        for (int ks = 0; ks < 2; ++ks) {
            int c0 = ks * 32 + g * 8;
            int sw = tok * 64 + (((c0 >> 3) ^ (tok & 7)) << 3);
            ag[ks] = *(const bf16x8*)&sGauT[sw];
        }
        const int kbg = (n0 >> 5) + (tb >> 1);
        const int half = tb & 1;
#pragma unroll
        for (int ob = 0; ob < 4; ++ob) {
            int o = ob * 16 + q;
            float bias = bv[o];
            f32x4 acc = {bias, bias, bias, bias};
            bf16x8 w0 = cvt8(&Wv[o * 64 + g * 8]);
            bf16x8 w1 = cvt8(&Wv[o * 64 + 32 + g * 8]);
            acc = __builtin_amdgcn_mfma_f32_16x16x32_bf16(ag[0], w0, acc, 0, 0, 0);
            acc = __builtin_amdgcn_mfma_f32_16x16x32_bf16(ag[1], w1, acc, 0, 0, 0);
            ushort4 v4;
            v4.x = f2b(acc[0]); v4.y = f2b(acc[1]);
            v4.z = f2b(acc[2]); v4.w = f2b(acc[3]);
#pragma unroll
            for (int j = 0; j < 4; ++j)
                Vtok[obase + (rowb + j) * 64 + o] = f2b(acc[j]);
            *(ushort4*)&Vswz[(((size_t)(b * 128 + kbg)) * 4 + ob) * 512 + lane * 8 + half * 4] = v4;
        }
    }
    __syncthreads();

    // Kfrag scatter: one ushort8 per thread
    {
        const int F = (wv * 64 + lane) * 8;
        const int kb2 = F >> 11;
        const int f = (F >> 9) & 3;
        const int l2 = (F >> 3) & 63;
        const int R = kb2 * 32 + ((f >> 1) << 4) + (l2 & 15);
        const int c0 = ((f & 1) << 5) + ((l2 >> 4) << 3);
        bf16x8 v = *(const bf16x8*)&kBuf[R * 64 + c0];
        *(bf16x8*)&Kfrag[(((size_t)(b * 128 + nb * 2 + kb2)) * 4 + f) * 512 + l2 * 8] = v;
    }
}

// ---------------------------------------------------------------------------
// Kernel 2: flash attention + LN1 + FFN + LN2.
// 256 blocks x 512 threads (8 waves) = 1 block/CU. Block = 64 queries
// (4 groups/wave), 8-way K-split, r14 LDS double-buffer staging — but with
// MANUAL COUNTED vmcnt (T4): issue stage(t+1), `s_waitcnt vmcnt(8)` (tile t
// ready, t+1 stays in flight), inline-asm ds_read_b128 (compiler cannot
// insert its own vmcnt(0) drain), lgkmcnt(0)+sched_barrier(0) per rule #18.
// ---------------------------------------------------------------------------
__global__ __launch_bounds__(512, 2) void attn_kernel(
    const u16* __restrict__ Qt, const u16* __restrict__ Kfrag,
    const u16* __restrict__ Vtok, const u16* __restrict__ Vswz,
    const float* __restrict__ ln1w, const float* __restrict__ ln1b,
    const float* __restrict__ ln2w, const float* __restrict__ ln2b,
    const float* __restrict__ W1, const float* __restrict__ b1,
    const float* __restrict__ W2, const float* __restrict__ b2,
    float* __restrict__ out)
{
    __shared__ __align__(16) u16 smem[8 * 2 * 4096]; // 128KB staging; aliased by sAcc post-loop
    __shared__ __align__(16) u16 sX[4 * 16 * 64];    // 8KB
    __shared__ float sL[8][64];                      // 2KB

    const int tid = threadIdx.x;
    const int wv = tid >> 6;          // 0..7 (K-split)
    const int lane = tid & 63;
    const int q = lane & 15, g = lane >> 4;
    const int bid = blockIdx.x;       // 0..255
    const int xcd = bid & 7;
    const int b = xcd >> 1;
    const int qb = ((bid >> 3) << 1) | (xcd & 1);   // 0..63
    const int q0 = qb * 64;
    const size_t tb_ = (size_t)b * NTOK * 64;

    // Q fragments for 4 query groups (Qt pre-scaled to exp2 domain)
    bf16x8 qf[4][2];
#pragma unroll
    for (int gi = 0; gi < 4; ++gi) {
        const size_t r = tb_ + (size_t)(q0 + gi * 16 + q) * 64;
        qf[gi][0] = *(const bf16x8*)&Qt[r + g * 8];
        qf[gi][1] = *(const bf16x8*)&Qt[r + 32 + g * 8];
    }

    f32x4 zero4 = {0.f, 0.f, 0.f, 0.f};
    f32x4 acc[4][4];
#pragma unroll
    for (int gi = 0; gi < 4; ++gi)
#pragma unroll
        for (int cb = 0; cb < 4; ++cb) acc[gi][cb] = zero4;
    float l[4] = {0.f, 0.f, 0.f, 0.f};

    const int kbeg = wv * 512;
    const size_t kvb = ((size_t)(b * 128 + (kbeg >> 5))) * 2048;
    const u16* gK = Kfrag + kvb + lane * 8;
    const u16* gV = Vswz + kvb + lane * 8;
    u16* stW = &smem[wv * 8192];
    u16* lK = stW + lane * 8;

    // ---- prologue: stage tile 0 into buffer 0 ----
#pragma unroll
    for (int i = 0; i < 4; ++i) GLD_LDS(gK + i * 512, lK + i * 512);
#pragma unroll
    for (int i = 0; i < 4; ++i) GLD_LDS(gV + i * 512, lK + 2048 + i * 512);

    for (int it = 0; it < 16; ++it) {
        const int cur = it & 1;
        // ---- issue next-tile stage into the other buffer FIRST ----
        {
            const int tn = (it < 15) ? it + 1 : 15;   // last iter: harmless re-stage
            const u16* gk = gK + (size_t)tn * 2048;
            const u16* gv = gV + (size_t)tn * 2048;
            u16* lk = lK + (cur ^ 1) * 4096;
#pragma unroll
            for (int i = 0; i < 4; ++i) GLD_LDS(gk + i * 512, lk + i * 512);
#pragma unroll
            for (int i = 0; i < 4; ++i) GLD_LDS(gv + i * 512, lk + 2048 + i * 512);
        }
        // counted wait: tile t complete, the 8 just-issued t+1 loads in flight
        asm volatile("s_waitcnt vmcnt(8)" ::: "memory");

        // inline-asm ds_read of current tile (compiler can't add vmcnt(0))
        lds_cu16* sb = (lds_cu16*)(stW + cur * 4096 + lane * 8);
        bf16x8 kf00, kf01, kf10, kf11, vf0, vf1, vf2, vf3;
        asm volatile("ds_read_b128 %0, %1 offset:0"    : "=v"(kf00) : "v"(sb));
        asm volatile("ds_read_b128 %0, %1 offset:1024" : "=v"(kf01) : "v"(sb));
        asm volatile("ds_read_b128 %0, %1 offset:2048" : "=v"(kf10) : "v"(sb));
        asm volatile("ds_read_b128 %0, %1 offset:3072" : "=v"(kf11) : "v"(sb));
        asm volatile("ds_read_b128 %0, %1 offset:4096" : "=v"(vf0)  : "v"(sb));
        asm volatile("ds_read_b128 %0, %1 offset:5120" : "=v"(vf1)  : "v"(sb));
        asm volatile("ds_read_b128 %0, %1 offset:6144" : "=v"(vf2)  : "v"(sb));
        asm volatile("ds_read_b128 %0, %1 offset:7168" : "=v"(vf3)  : "v"(sb));
        asm volatile("s_waitcnt lgkmcnt(0)" ::: "memory");
        __builtin_amdgcn_sched_barrier(0);   // rule #18: fence MFMA behind lgkmcnt

        // ---- 4 independent query groups over this 32-key tile ----
#pragma unroll
        for (int gi = 0; gi < 4; ++gi) {
            f32x4 s0 = __builtin_amdgcn_mfma_f32_16x16x32_bf16(kf00, qf[gi][0], zero4, 0, 0, 0);
            s0 = __builtin_amdgcn_mfma_f32_16x16x32_bf16(kf01, qf[gi][1], s0, 0, 0, 0);
            f32x4 s1 = __builtin_amdgcn_mfma_f32_16x16x32_bf16(kf10, qf[gi][0], zero4, 0, 0, 0);
            s1 = __builtin_amdgcn_mfma_f32_16x16x32_bf16(kf11, qf[gi][1], s1, 0, 0, 0);

            float p0 = __builtin_exp2f(s0[0]);
            float p1 = __builtin_exp2f(s0[1]);
            float p2 = __builtin_exp2f(s0[2]);
            float p3 = __builtin_exp2f(s0[3]);
            float p4 = __builtin_exp2f(s1[0]);
            float p5 = __builtin_exp2f(s1[1]);
            float p6 = __builtin_exp2f(s1[2]);
            float p7 = __builtin_exp2f(s1[3]);
            l[gi] += ((p0 + p1) + (p2 + p3)) + ((p4 + p5) + (p6 + p7));
            u32 pwv[4] = {pk2(p0, p1), pk2(p2, p3), pk2(p4, p5), pk2(p6, p7)};
            bf16x8 pf = __builtin_bit_cast(bf16x8, *(const bf16x8*)pwv);
            acc[gi][0] = __builtin_amdgcn_mfma_f32_16x16x32_bf16(vf0, pf, acc[gi][0], 0, 0, 0);
            acc[gi][1] = __builtin_amdgcn_mfma_f32_16x16x32_bf16(vf1, pf, acc[gi][1], 0, 0, 0);
            acc[gi][2] = __builtin_amdgcn_mfma_f32_16x16x32_bf16(vf2, pf, acc[gi][2], 0, 0, 0);
            acc[gi][3] = __builtin_amdgcn_mfma_f32_16x16x32_bf16(vf3, pf, acc[gi][3], 0, 0, 0);
        }
    }

    // cross-lane l reduction (g-lanes of each query), once
#pragma unroll
    for (int gi = 0; gi < 4; ++gi) {
        l[gi] += __shfl_xor(l[gi], 16);
        l[gi] += __shfl_xor(l[gi], 32);
    }

    // drain in-flight stage writes, then repurpose staging LDS as sAcc
    asm volatile("s_waitcnt vmcnt(0)" ::: "memory");
    __syncthreads();
    float* sAcc = (float*)smem;   // [4][64][68] floats = 69632 B (aliases dead staging)
#define SACC(w_, r_) (&sAcc[(((w_) * 64) + (r_)) * 68])

    // ---- stage 1: waves 4-7 publish partials ----
    if (wv >= 4) {
        const int s = wv - 4;
#pragma unroll
        for (int gi = 0; gi < 4; ++gi) {
            sL[wv][gi * 16 + q] = l[gi];
#pragma unroll
            for (int cb = 0; cb < 4; ++cb)
                *(f32x4*)&SACC(s, gi * 16 + q)[cb * 16 + g * 4] = acc[gi][cb];
        }
    }
    __syncthreads();

    // ---- stage 2: waves 0-3 add partner (wv+4), publish ----
    if (wv < 4) {
#pragma unroll
        for (int gi = 0; gi < 4; ++gi) {
            l[gi] += sL[wv + 4][gi * 16 + q];
            sL[wv][gi * 16 + q] = l[gi];
#pragma unroll
            for (int cb = 0; cb < 4; ++cb) {
                f32x4 pa = *(const f32x4*)&SACC(wv, gi * 16 + q)[cb * 16 + g * 4];
#pragma unroll
                for (int j = 0; j < 4; ++j) acc[gi][cb][j] += pa[j];
                *(f32x4*)&SACC(wv, gi * 16 + q)[cb * 16 + g * 4] = acc[gi][cb];
            }
        }
    }
    __syncthreads();
    if (wv >= 4) return;

    // ---- stage 3: waves 0-3, each finishes 16 queries qe = wv*16+q ----
    const int qe = wv * 16 + q;
    const int n_q = q0 + qe;

    float L = sL[0][qe] + sL[1][qe] + sL[2][qe] + sL[3][qe];
    f32x4 o[4];
#pragma unroll
    for (int cb = 0; cb < 4; ++cb) o[cb] = zero4;
#pragma unroll
    for (int w = 0; w < 4; ++w) {
#pragma unroll
        for (int cb = 0; cb < 4; ++cb) {
            f32x4 aw = *(const f32x4*)&SACC(w, qe)[cb * 16 + g * 4];
#pragma unroll
            for (int j = 0; j < 4; ++j) o[cb][j] += aw[j];
        }
    }

    float inv_l = 1.0f / L;
    float x1[4][4];
#pragma unroll
    for (int cb = 0; cb < 4; ++cb) {
        ushort4 vv = *(const ushort4*)&Vtok[tb_ + (size_t)n_q * 64 + cb * 16 + g * 4];
        x1[cb][0] = o[cb][0] * inv_l + b2f(vv.x);
        x1[cb][1] = o[cb][1] * inv_l + b2f(vv.y);
        x1[cb][2] = o[cb][2] * inv_l + b2f(vv.z);
        x1[cb][3] = o[cb][3] * inv_l + b2f(vv.w);
    }

    // LN1
    float s_ = 0.f;
#pragma unroll
    for (int cb = 0; cb < 4; ++cb)
        for (int j = 0; j < 4; ++j) s_ += x1[cb][j];
    s_ += __shfl_xor(s_, 16); s_ += __shfl_xor(s_, 32);
    float mean = s_ * (1.f / 64.f);
    float v_ = 0.f;
#pragma unroll
    for (int cb = 0; cb < 4; ++cb)
        for (int j = 0; j < 4; ++j) { float d = x1[cb][j] - mean; v_ += d * d; }
    v_ += __shfl_xor(v_, 16); v_ += __shfl_xor(v_, 32);
    float rstd = rsqrtf(v_ * (1.f / 64.f) + 1e-5f);

    float xh[4][4];
#pragma unroll
    for (int cb = 0; cb < 4; ++cb) {
        float4 lw = *(const float4*)&ln1w[cb * 16 + g * 4];
        float4 lb = *(const float4*)&ln1b[cb * 16 + g * 4];
        xh[cb][0] = (x1[cb][0] - mean) * rstd * lw.x + lb.x;
        xh[cb][1] = (x1[cb][1] - mean) * rstd * lw.y + lb.y;
        xh[cb][2] = (x1[cb][2] - mean) * rstd * lw.z + lb.z;
        xh[cb][3] = (x1[cb][3] - mean) * rstd * lw.w + lb.w;
    }

    // FFN layer 1 via per-wave LDS roundtrip
    u32* sXu = (u32*)sX;
    const int xwr = wv * 512 + q * 32;
#pragma unroll
    for (int cb = 0; cb < 4; ++cb) {
        sXu[xwr + cb * 8 + g * 2 + 0] = pack2(xh[cb][0], xh[cb][1]);
        sXu[xwr + cb * 8 + g * 2 + 1] = pack2(xh[cb][2], xh[cb][3]);
    }
    asm volatile("s_waitcnt lgkmcnt(0)" ::: "memory");
    __builtin_amdgcn_sched_barrier(0);
    const u16* xrp = &sX[wv * 1024 + q * 64 + g * 8];
    bf16x8 xb0 = *(const bf16x8*)&xrp[0];
    bf16x8 xb1 = *(const bf16x8*)&xrp[32];

    float h[4][4];
#pragma unroll
    for (int ob = 0; ob < 4; ++ob) {
        float4 bb = *(const float4*)&b1[ob * 16 + g * 4];
        f32x4 hacc = {bb.x, bb.y, bb.z, bb.w};
        bf16x8 w0 = cvt8(&W1[(size_t)(ob * 16 + q) * 64 + g * 8]);
        bf16x8 w1 = cvt8(&W1[(size_t)(ob * 16 + q) * 64 + 32 + g * 8]);
        hacc = __builtin_amdgcn_mfma_f32_16x16x32_bf16(w0, xb0, hacc, 0, 0, 0);
        hacc = __builtin_amdgcn_mfma_f32_16x16x32_bf16(w1, xb1, hacc, 0, 0, 0);
#pragma unroll
        for (int j = 0; j < 4; ++j) h[ob][j] = fmaxf(hacc[j], 0.f);
    }

#pragma unroll
    for (int ob = 0; ob < 4; ++ob) {
        sXu[xwr + ob * 8 + g * 2 + 0] = pack2(h[ob][0], h[ob][1]);
        sXu[xwr + ob * 8 + g * 2 + 1] = pack2(h[ob][2], h[ob][3]);
    }
    asm volatile("s_waitcnt lgkmcnt(0)" ::: "memory");
    __builtin_amdgcn_sched_barrier(0);
    bf16x8 hb0 = *(const bf16x8*)&xrp[0];
    bf16x8 hb1 = *(const bf16x8*)&xrp[32];

    float f_[4][4];
#pragma unroll
    for (int cb = 0; cb < 4; ++cb) {
        float4 bb = *(const float4*)&b2[cb * 16 + g * 4];
        f32x4 yacc = {bb.x, bb.y, bb.z, bb.w};
        bf16x8 w0 = cvt8(&W2[(size_t)(cb * 16 + q) * 64 + g * 8]);
        bf16x8 w1 = cvt8(&W2[(size_t)(cb * 16 + q) * 64 + 32 + g * 8]);
        yacc = __builtin_amdgcn_mfma_f32_16x16x32_bf16(w0, hb0, yacc, 0, 0, 0);
        yacc = __builtin_amdgcn_mfma_f32_16x16x32_bf16(w1, hb1, yacc, 0, 0, 0);
#pragma unroll
        for (int j = 0; j < 4; ++j) f_[cb][j] = xh[cb][j] + yacc[j];
    }

    // LN2
    float s2 = 0.f;
#pragma unroll
    for (int cb = 0; cb < 4; ++cb)
        for (int j = 0; j < 4; ++j) s2 += f_[cb][j];
    s2 += __shfl_xor(s2, 16); s2 += __shfl_xor(s2, 32);
    float mean2 = s2 * (1.f / 64.f);
    float v2 = 0.f;
#pragma unroll
    for (int cb = 0; cb < 4; ++cb)
        for (int j = 0; j < 4; ++j) { float d = f_[cb][j] - mean2; v2 += d * d; }
    v2 += __shfl_xor(v2, 16); v2 += __shfl_xor(v2, 32);
    float rstd2 = rsqrtf(v2 * (1.f / 64.f) + 1e-5f);

#pragma unroll
    for (int cb = 0; cb < 4; ++cb) {
        float4 lw = *(const float4*)&ln2w[cb * 16 + g * 4];
        float4 lb = *(const float4*)&ln2b[cb * 16 + g * 4];
        float o0 = (f_[cb][0] - mean2) * rstd2 * lw.x + lb.x;
        float o1 = (f_[cb][1] - mean2) * rstd2 * lw.y + lb.y;
        float o2 = (f_[cb][2] - mean2) * rstd2 * lw.z + lb.z;
        float o3 = (f_[cb][3] - mean2) * rstd2 * lw.w + lb.w;
        out[(size_t)(b * 64 + cb * 16 + g * 4 + 0) * NTOK + n_q] = o0;
        out[(size_t)(b * 64 + cb * 16 + g * 4 + 1) * NTOK + n_q] = o1;
        out[(size_t)(b * 64 + cb * 16 + g * 4 + 2) * NTOK + n_q] = o2;
        out[(size_t)(b * 64 + cb * 16 + g * 4 + 3) * NTOK + n_q] = o3;
    }
}

extern "C" void kernel_launch(void* const* d_in, const int* in_sizes, int n_in,
                              void* d_out, int out_size, void* d_ws, size_t ws_size,
                              hipStream_t stream) {
    const float* seg = (const float*)d_in[0];
    const float* gau = (const float*)d_in[1];
    const float* Wq = (const float*)d_in[2];
    const float* bq = (const float*)d_in[3];
    const float* Wk = (const float*)d_in[4];
    const float* bk = (const float*)d_in[5];
    const float* Wv = (const float*)d_in[6];
    const float* bv = (const float*)d_in[7];
    const float* ln1w = (const float*)d_in[8];
    const float* ln1b = (const float*)d_in[9];
    const float* ln2w = (const float*)d_in[10];
    const float* ln2b = (const float*)d_in[11];
    const float* W1 = (const float*)d_in[12];
    const float* b1 = (const float*)d_in[13];
    const float* W2 = (const float*)d_in[14];
    const float* b2 = (const float*)d_in[15];

    u16* Qt = (u16*)d_ws;
    u16* Kfrag = Qt + (size_t)4 * NTOK * 64;    // [b][kb(128)][f(4)][lane(64)][8]
    u16* Vtok = Kfrag + (size_t)4 * NTOK * 64;
    u16* Vswz = Vtok + (size_t)4 * NTOK * 64;   // [b][kb(128)][cb(4)][lane(64)][8]
    float* outp = (float*)d_out;

    hipLaunchKernelGGL(qkv_kernel, dim3(256), dim3(512), 0, stream,
                       seg, gau, Wq, bq, Wk, bk, Wv, bv, Qt, Kfrag, Vtok, Vswz);
    hipLaunchKernelGGL(attn_kernel, dim3(256), dim3(512), 0, stream,
                       Qt, Kfrag, Vtok, Vswz, ln1w, ln1b, ln2w, ln2b,
                       W1, b1, W2, b2, outp);
}